// Round 8
// baseline (24.015 us; speedup 1.0000x reference)
//
#include <hip/hip_runtime.h>
#include <hip/hip_bf16.h>

// Problem constants (match reference)
#define MB 4096      // B rows
#define MD 4096      // D classes
#define MP 8         // P positives per row
#define MARGIN 0.5f
#define NB MB        // one block per row
#define GRP 64       // blocks per group
#define NG (NB / GRP)            // 64 groups
#define CNT_STRIDE 32            // ints between group counters (128 B line)

typedef float f32x4 __attribute__((ext_vector_type(4)));

// Fused kernel, R7's proven compute body + hierarchical ticket finish using
// RELAXED agent atomics only.
//
// R4/R5/R6 post-mortem: ACQ_REL agent-scope atomics cost ~35ns EACH,
// serialized device-wide (per-XCD L2 maintenance), independent of address
// spreading (R6 falsified line contention). Relaxed agent atomics carry no
// maintenance; ordering is hand-rolled: atomic_store(relaxed) partial ->
// s_waitcnt vmcnt(0) (store retired at the coherent point) ->
// fetch_add(relaxed) ticket. A ticket observed == fan-in-1 therefore implies
// all predecessors' stores are globally visible.
// Reductions are fixed-order shuffle trees => deterministic.
__global__ __launch_bounds__(256) void margin_fused_kernel(
    const float* __restrict__ x,
    const int* __restrict__ pos_ids,
    int* __restrict__ gcnt,        // NG counters, stride CNT_STRIDE (memset 0)
    int* __restrict__ gcnt2,       // 1 counter (memset 0)
    float* __restrict__ partials,  // NB floats
    double* __restrict__ gsum,     // NG doubles
    float* __restrict__ out)
{
    const int row = blockIdx.x;
    const int t = threadIdx.x;
    const int lane = t & 63;
    const int wave = t >> 6;
    const float* __restrict__ xr = x + (size_t)row * MD;

    // Longest dependency chain first: pos_ids -> gather -> shfl broadcast.
    const int p = pos_ids[row * MP + (lane & 7)];

    // Independent streaming loads — issue early, overlap with the gather.
    const f32x4* __restrict__ xr4 = reinterpret_cast<const f32x4*>(xr);
    const f32x4 v0 = __builtin_nontemporal_load(xr4 + t);
    const f32x4 v1 = __builtin_nontemporal_load(xr4 + 256 + t);
    const f32x4 v2 = __builtin_nontemporal_load(xr4 + 512 + t);
    const f32x4 v3 = __builtin_nontemporal_load(xr4 + 768 + t);

    const float xg = xr[p];   // 8 unique addresses per wave (cache hits)

    // Per-wave broadcast of thresholds t_k = x[pos_k] - MARGIN (no barrier).
    float th[MP];
    int   pi[MP];
#pragma unroll
    for (int k = 0; k < MP; ++k) {
        th[k] = __shfl(xg, k, 64) - MARGIN;
        pi[k] = __shfl(p, k, 64);
    }

    const float vv[16] = { v0.x, v0.y, v0.z, v0.w,
                           v1.x, v1.y, v1.z, v1.w,
                           v2.x, v2.y, v2.z, v2.w,
                           v3.x, v3.y, v3.z, v3.w };

    float acc0 = 0.0f, acc1 = 0.0f;   // two chains for ILP
#pragma unroll
    for (int j = 0; j < 16; ++j) {
        const float v = vv[j];
#pragma unroll
        for (int k = 0; k < MP; k += 2) {
            acc0 += fmaxf(0.0f, v - th[k]);
            acc1 += fmaxf(0.0f, v - th[k + 1]);
        }
    }

    // Positive-column correction: lane l (<8) subtracts the contribution of
    // anchor column pos[l] (dedup duplicates: y[i,d]=1 regardless of repeats).
    if (t < MP) {
        bool dup = false;
#pragma unroll
        for (int k2 = 0; k2 < MP; ++k2) dup = dup || (k2 < t && pi[k2] == pi[t]);
        if (!dup) {
            const float xk = th[t] + MARGIN;   // = x[row, pos_t]
#pragma unroll
            for (int j = 0; j < MP; ++j)
                acc0 -= fmaxf(0.0f, xk - th[j]);
        }
    }

    float acc = acc0 + acc1;
#pragma unroll
    for (int off = 32; off > 0; off >>= 1)
        acc += __shfl_down(acc, off, 64);

    __shared__ float s_part[4];
    if (lane == 0) s_part[wave] = acc;
    __syncthreads();

    // ---- hierarchical deterministic finish (relaxed atomics), wave 0 ----
    if (t < 64) {
        const int g = row / GRP;

        int gticket = -1;
        if (t == 0) {
            const float bp = s_part[0] + s_part[1] + s_part[2] + s_part[3];
            __hip_atomic_store(&partials[row], bp,
                               __ATOMIC_RELAXED, __HIP_MEMORY_SCOPE_AGENT);
            // hand-rolled release: drain the store to the coherent point
            asm volatile("s_waitcnt vmcnt(0)" ::: "memory");
            gticket = __hip_atomic_fetch_add(&gcnt[g * CNT_STRIDE], 1,
                               __ATOMIC_RELAXED, __HIP_MEMORY_SCOPE_AGENT);
        }
        gticket = __shfl(gticket, 0, 64);

        if (gticket == GRP - 1) {
            // group finisher: sum this group's 64 partials (fixed order)
            double d = (double)__hip_atomic_load(&partials[g * GRP + t],
                               __ATOMIC_RELAXED, __HIP_MEMORY_SCOPE_AGENT);
#pragma unroll
            for (int off = 32; off > 0; off >>= 1)
                d += __shfl_down(d, off, 64);

            int t2 = -1;
            if (t == 0) {
                __hip_atomic_store(&gsum[g], d,
                                   __ATOMIC_RELAXED, __HIP_MEMORY_SCOPE_AGENT);
                asm volatile("s_waitcnt vmcnt(0)" ::: "memory");
                t2 = __hip_atomic_fetch_add(gcnt2, 1,
                                   __ATOMIC_RELAXED, __HIP_MEMORY_SCOPE_AGENT);
            }
            t2 = __shfl(t2, 0, 64);

            if (t2 == NG - 1) {
                // global finisher: sum 64 group sums (fixed order)
                double s = __hip_atomic_load(&gsum[t],
                                   __ATOMIC_RELAXED, __HIP_MEMORY_SCOPE_AGENT);
#pragma unroll
                for (int off = 32; off > 0; off >>= 1)
                    s += __shfl_down(s, off, 64);
                if (t == 0) {
                    const double count = (double)MB * (double)MP * (double)(MD - MP);
                    out[0] = (float)(s / count);
                }
            }
        }
    }
}

extern "C" void kernel_launch(void* const* d_in, const int* in_sizes, int n_in,
                              void* d_out, int out_size, void* d_ws, size_t ws_size,
                              hipStream_t stream) {
    const float* x = (const float*)d_in[0];
    // d_in[1] is y, redundant with pos_ids — not read (halves HBM traffic).
    const int* pos_ids = (const int*)d_in[2];
    float* out = (float*)d_out;

    // d_ws layout:
    //   [0,      8192)  gcnt[64] strided 128 B   (memset to 0)
    //   [8192,   8320)  gcnt2                    (memset to 0)
    //   [16384, 32768)  partials[4096] floats    (written before read)
    //   [32768, 33280)  gsum[64] doubles         (written before read)
    char* ws = (char*)d_ws;
    int*    gcnt     = (int*)ws;
    int*    gcnt2    = (int*)(ws + 8192);
    float*  partials = (float*)(ws + 16384);
    double* gsum     = (double*)(ws + 32768);

    hipMemsetAsync(ws, 0, 8320, stream);
    margin_fused_kernel<<<NB, 256, 0, stream>>>(x, pos_ids, gcnt, gcnt2,
                                                partials, gsum, out);
}

// Round 9
// 17.856 us; speedup vs baseline: 1.3449x; 1.3449x over previous
//
#include <hip/hip_runtime.h>
#include <hip/hip_bf16.h>

// Problem constants (match reference)
#define MB 4096      // B rows
#define MD 4096      // D classes
#define MP 8         // P positives per row
#define MARGIN 0.5f

typedef float f32x4 __attribute__((ext_vector_type(4)));

// Stage 1: one block (256 threads) per row, grid 4096.
//
// Identity: relu(MARGIN + v - x_pos[k]) = max(v, th_k) - th_k,
//           th_k = x_pos[k] - MARGIN.
// Summed over k and the thread's 16 columns:
//   thread_acc = sum_j sum_k max(v_j, th_k)  -  16 * sum_k th_k
// => hot loop is 2 VALU ops/hinge (v_max + v_add), no per-hinge subtract.
// (R4/R5 cross-check: compute body carries ~10.5us integrated VALU-busy vs
// ~8us memory floor => stage 1 is VALU-bound; this cuts the dominant term.)
//
// The positive-column correction depends only on the 8 anchors and is folded
// into lanes 0..7 (nothing serial on the block-exit path).
// Fused single-kernel finishes were tried and rejected: ACQ_REL agent atomics
// serialize ~35ns/op device-wide (R5/R6); even relaxed+vmcnt tickets cost
// +5us vs a plain second dispatch (R8).
__global__ __launch_bounds__(256) void margin_rows_kernel(
    const float* __restrict__ x,
    const int* __restrict__ pos_ids,
    float* __restrict__ ws)
{
    const int row = blockIdx.x;
    const int t = threadIdx.x;
    const int lane = t & 63;
    const int wave = t >> 6;
    const float* __restrict__ xr = x + (size_t)row * MD;

    // Longest dependency chain first: pos_ids -> gather -> shfl broadcast.
    const int p = pos_ids[row * MP + (lane & 7)];

    // Independent streaming loads — issue early, overlap with the gather.
    const f32x4* __restrict__ xr4 = reinterpret_cast<const f32x4*>(xr);
    const f32x4 v0 = __builtin_nontemporal_load(xr4 + t);
    const f32x4 v1 = __builtin_nontemporal_load(xr4 + 256 + t);
    const f32x4 v2 = __builtin_nontemporal_load(xr4 + 512 + t);
    const f32x4 v3 = __builtin_nontemporal_load(xr4 + 768 + t);

    const float xg = xr[p];   // 8 unique addresses per wave (cache hits)

    // Per-wave broadcast of thresholds th_k = x[pos_k] - MARGIN (no barrier).
    float th[MP];
    int   pi[MP];
#pragma unroll
    for (int k = 0; k < MP; ++k) {
        th[k] = __shfl(xg, k, 64) - MARGIN;
        pi[k] = __shfl(p, k, 64);
    }
    float sum_th = 0.0f;
#pragma unroll
    for (int k = 0; k < MP; ++k) sum_th += th[k];

    const float vv[16] = { v0.x, v0.y, v0.z, v0.w,
                           v1.x, v1.y, v1.z, v1.w,
                           v2.x, v2.y, v2.z, v2.w,
                           v3.x, v3.y, v3.z, v3.w };

    float acc0 = 0.0f, acc1 = 0.0f;   // two chains for ILP
#pragma unroll
    for (int j = 0; j < 16; ++j) {
        const float v = vv[j];
#pragma unroll
        for (int k = 0; k < MP; k += 2) {
            acc0 += fmaxf(v, th[k]);        // v_max + v_add only
            acc1 += fmaxf(v, th[k + 1]);
        }
    }
    // remove the -th_k terms in one shot: 16 columns x sum_th
    acc0 -= 16.0f * sum_th;

    // Positive-column correction: lane l (<8) subtracts the contribution of
    // anchor column pos[l] (dedup duplicates: y[i,d]=1 regardless of repeats).
    if (t < MP) {
        bool dup = false;
#pragma unroll
        for (int k2 = 0; k2 < MP; ++k2) dup = dup || (k2 < t && pi[k2] == pi[t]);
        if (!dup) {
            const float xk = th[t] + MARGIN;   // = x[row, pos_t]
#pragma unroll
            for (int j = 0; j < MP; ++j)
                acc0 -= fmaxf(0.0f, xk - th[j]);
        }
    }

    float acc = acc0 + acc1;
#pragma unroll
    for (int off = 32; off > 0; off >>= 1)
        acc += __shfl_down(acc, off, 64);

    __shared__ float s_part[4];
    if (lane == 0) s_part[wave] = acc;
    __syncthreads();
    if (t == 0)
        ws[row] = s_part[0] + s_part[1] + s_part[2] + s_part[3];
}

// Stage 2: one block reduces MB partials (double accumulation, fixed order).
__global__ __launch_bounds__(256) void margin_final_kernel(
    const float* __restrict__ ws,
    float* __restrict__ out)
{
    const int t = threadIdx.x;
    double acc = 0.0;
#pragma unroll
    for (int it = 0; it < MB / 256; ++it)
        acc += (double)ws[it * 256 + t];

#pragma unroll
    for (int off = 32; off > 0; off >>= 1)
        acc += __shfl_down(acc, off, 64);

    __shared__ double s_part[4];
    const int wave = t >> 6;
    if ((t & 63) == 0) s_part[wave] = acc;
    __syncthreads();
    if (t == 0) {
        const double tot = s_part[0] + s_part[1] + s_part[2] + s_part[3];
        const double count = (double)MB * (double)MP * (double)(MD - MP);
        out[0] = (float)(tot / count);
    }
}

extern "C" void kernel_launch(void* const* d_in, const int* in_sizes, int n_in,
                              void* d_out, int out_size, void* d_ws, size_t ws_size,
                              hipStream_t stream) {
    const float* x = (const float*)d_in[0];
    // d_in[1] is y, redundant with pos_ids — not read (halves HBM traffic).
    const int* pos_ids = (const int*)d_in[2];
    float* out = (float*)d_out;
    float* ws = (float*)d_ws;  // MB floats = 16 KB of scratch

    margin_rows_kernel<<<MB, 256, 0, stream>>>(x, pos_ids, ws);
    margin_final_kernel<<<1, 256, 0, stream>>>(ws, out);
}